// Round 1
// baseline (100.236 us; speedup 1.0000x reference)
//
#include <hip/hip_runtime.h>

#define SIZE 512
#define NTRI 512

#pragma clang fp contract(off)

__device__ __forceinline__ float lin_at(int i) {
    // Replicates jnp.linspace(-1, 1, 512): for i < 511,
    // s = i/511 (f32 correctly-rounded div), out = (-1)*(1-s) + 1*s = s - (1-s).
    // Endpoint i == 511 is concatenated as exactly `stop` = 1.0.
    if (i == SIZE - 1) return 1.0f;
    float s = __fdiv_rn((float)i, 511.0f);
    float u = 1.0f - s;
    return s - u;
}

__global__ __launch_bounds__(256) void render_kernel(const float* __restrict__ tris,
                                                     float* __restrict__ out) {
#pragma clang fp contract(off)
    __shared__ float4 sf0[NTRI];  // Ax, Ay, Bx, By
    __shared__ float4 sf1[NTRI];  // Cx, Cy, Az, rsw
    __shared__ float4 sf2[NTRI];  // Bz, Cz, -, -
    __shared__ int4   sbb[NTRI];  // bbox x_lo, y_lo, x_hi, y_hi (empty if invalid w)
    __shared__ float  sred[4];

    const int tx = threadIdx.x, ty = threadIdx.y;
    const int tid = ty * 16 + tx;

    // ---- stage + preprocess all triangles into LDS; track local z-min ----
    float zm = 1e30f;
    for (int t = tid; t < NTRI; t += 256) {
        const float* p = tris + t * 9;
        float a0 = p[0], a1 = p[1], a2 = p[2];
        float b0 = p[3], b1 = p[4], b2 = p[5];
        float c0 = p[6], c1 = p[7], c2 = p[8];

        float w = (b0 - a0) * (c1 - a1) - (b1 - a1) * (c0 - a0);
        bool vw = fabsf(w) > 1e-8f;
        float sw = vw ? w : 1.0f;
        float rsw = 1.0f / sw;

        float lox = fminf(fminf(a0, b0), c0);
        float loy = fminf(fminf(a1, b1), c1);
        float hix = fmaxf(fmaxf(a0, b0), c0);
        float hiy = fmaxf(fmaxf(a1, b1), c1);
        // ((clip(v,-1,1) + 1.0) * 0.5) * 512, truncated toward zero (astype int32)
        int bb0 = (int)((fminf(fmaxf(lox, -1.0f), 1.0f) + 1.0f) * 0.5f * 512.0f);
        int bb1 = (int)((fminf(fmaxf(loy, -1.0f), 1.0f) + 1.0f) * 0.5f * 512.0f);
        int bb2 = (int)((fminf(fmaxf(hix, -1.0f), 1.0f) + 1.0f) * 0.5f * 512.0f);
        int bb3 = (int)((fminf(fmaxf(hiy, -1.0f), 1.0f) + 1.0f) * 0.5f * 512.0f);
        if (!vw) { bb0 = 0; bb2 = 0; }  // valid_w == false -> never covered

        sbb[t] = make_int4(bb0, bb1, bb2, bb3);
        sf0[t] = make_float4(a0, a1, b0, b1);
        sf1[t] = make_float4(c0, c1, a2, rsw);
        sf2[t] = make_float4(b2, c2, 0.0f, 0.0f);

        zm = fminf(zm, fminf(a2, fminf(b2, c2)));
    }
    // zmin block reduction (exact: min has no rounding)
    for (int off = 32; off; off >>= 1) zm = fminf(zm, __shfl_xor(zm, off));
    if ((tid & 63) == 0) sred[tid >> 6] = zm;
    __syncthreads();
    const float zmin = fminf(fminf(sred[0], sred[1]), fminf(sred[2], sred[3]));

    // ---- per-pixel loop over all triangles ----
    const int j = blockIdx.x * 16 + tx;  // yi (fast output axis)
    const int i = blockIdx.y * 16 + ty;  // xi
    const float px = lin_at(i);
    const float py = lin_at(j);

    float best = zmin;
    int   bi = -1;
    float bw1 = 0.0f, bw2 = 0.0f;

    for (int t = 0; t < NTRI; ++t) {
        int4 bb = sbb[t];
        if (i >= bb.x && i < bb.z && j >= bb.y && j < bb.w) {
            float4 f0 = sf0[t];
            float4 f1 = sf1[t];
            // Edge functions: EXACT op-order replication of the reference, no FMA.
            float dax = f0.x - px, day = f0.y - py;
            float dbx = f0.z - px, dby = f0.w - py;
            float dcx = f1.x - px, dcy = f1.y - py;
            float pAB = dax * dby - day * dbx;
            float pBC = dbx * dcy - dby * dcx;
            float pCA = dcx * day - dcy * dax;
            if (pAB > 0.0f && pBC > 0.0f && pCA > 0.0f) {
                float4 f2 = sf2[t];
                float w1 = pAB * f1.w;
                float w2 = pBC * f1.w;
                float w3 = 1.0f - w1 - w2;
                float z = w1 * f1.z + w2 * f2.x + w3 * f2.y;
                if (z >= best) { best = z; bi = t; bw1 = w1; bw2 = w2; }
            }
        }
    }

    // ---- epilogue: interpolate winner, write pixel ----
    float4 o = make_float4(0.0f, 0.0f, 0.0f, 0.0f);
    if (bi >= 0) {
        float4 f0 = sf0[bi];
        float4 f1 = sf1[bi];
        float4 f2 = sf2[bi];
        float w3 = 1.0f - bw1 - bw2;
        float x = bw1 * f0.x + bw2 * f0.z + w3 * f1.x;
        float y = bw1 * f0.y + bw2 * f0.w + w3 * f1.y;
        float z = bw1 * f1.z + bw2 * f2.x + w3 * f2.y;
        o = make_float4(x, y, z, 1.0f);
    }
    ((float4*)out)[i * SIZE + j] = o;
}

extern "C" void kernel_launch(void* const* d_in, const int* in_sizes, int n_in,
                              void* d_out, int out_size, void* d_ws, size_t ws_size,
                              hipStream_t stream) {
    const float* tris = (const float*)d_in[0];
    float* out = (float*)d_out;
    dim3 grid(SIZE / 16, SIZE / 16, 1);
    dim3 block(16, 16, 1);
    render_kernel<<<grid, block, 0, stream>>>(tris, out);
}

// Round 2
// 49.123 us; speedup vs baseline: 2.0405x; 2.0405x over previous
//
#include <hip/hip_runtime.h>

#define SIZE 512
#define NTRI 512

#pragma clang fp contract(off)

__device__ __forceinline__ float lin_at(int i) {
    // Replicates jnp.linspace(-1, 1, 512): for i < 511,
    // s = i/511 (f32 correctly-rounded div), out = (-1)*(1-s) + 1*s = s - (1-s).
    // Endpoint i == 511 is concatenated as exactly `stop` = 1.0.
    if (i == SIZE - 1) return 1.0f;
    float s = __fdiv_rn((float)i, 511.0f);
    float u = 1.0f - s;
    return s - u;
}

__global__ __launch_bounds__(256) void render_kernel(const float* __restrict__ tris,
                                                     float* __restrict__ out) {
#pragma clang fp contract(off)
    __shared__ float4 sf0[NTRI];  // Ax, Ay, Bx, By
    __shared__ float4 sf1[NTRI];  // Cx, Cy, Az, rsw
    __shared__ float2 sf2[NTRI];  // Bz, Cz
    __shared__ int4   sbb[NTRI];  // bbox x_lo, y_lo, x_hi, y_hi (empty if invalid w)
    __shared__ int    slist[NTRI];
    __shared__ unsigned long long smask[8];
    __shared__ float  sred[4];

    const int tx = threadIdx.x, ty = threadIdx.y;
    const int tid = ty * 16 + tx;
    const int lane = tid & 63, wv = tid >> 6;

    const int bi0 = blockIdx.y * 16;  // xi range of this block
    const int bj0 = blockIdx.x * 16;  // yi range of this block

    // ---- phase 1: stage + preprocess all triangles; candidate ballot ----
    float zm = 1e30f;
    for (int r = 0; r < 2; ++r) {
        const int t = tid + r * 256;
        const float* p = tris + t * 9;
        float a0 = p[0], a1 = p[1], a2 = p[2];
        float b0 = p[3], b1 = p[4], b2 = p[5];
        float c0 = p[6], c1 = p[7], c2 = p[8];

        float w = (b0 - a0) * (c1 - a1) - (b1 - a1) * (c0 - a0);
        bool vw = fabsf(w) > 1e-8f;
        float sw = vw ? w : 1.0f;
        float rsw = 1.0f / sw;

        float lox = fminf(fminf(a0, b0), c0);
        float loy = fminf(fminf(a1, b1), c1);
        float hix = fmaxf(fmaxf(a0, b0), c0);
        float hiy = fmaxf(fmaxf(a1, b1), c1);
        // ((clip(v,-1,1) + 1.0) * 0.5) * 512, truncated toward zero (astype int32)
        int bb0 = (int)((fminf(fmaxf(lox, -1.0f), 1.0f) + 1.0f) * 0.5f * 512.0f);
        int bb1 = (int)((fminf(fmaxf(loy, -1.0f), 1.0f) + 1.0f) * 0.5f * 512.0f);
        int bb2 = (int)((fminf(fmaxf(hix, -1.0f), 1.0f) + 1.0f) * 0.5f * 512.0f);
        int bb3 = (int)((fminf(fmaxf(hiy, -1.0f), 1.0f) + 1.0f) * 0.5f * 512.0f);
        if (!vw) { bb0 = 0; bb2 = 0; }  // valid_w == false -> never covered

        sbb[t] = make_int4(bb0, bb1, bb2, bb3);
        sf0[t] = make_float4(a0, a1, b0, b1);
        sf1[t] = make_float4(c0, c1, a2, rsw);
        sf2[t] = make_float2(b2, c2);

        zm = fminf(zm, fminf(a2, fminf(b2, c2)));

        // Candidate cull (exact): all-edges-positive needs w > 0 algebraically
        // (pAB+pBC+pCA == w); -1e-4 guard covers fp rounding of slivers.
        // Block bbox intersect == exists a pixel in this tile passing inbox.
        bool cand = (w > -1e-4f) &&
                    (bb0 < bi0 + 16) && (bb2 > bi0) &&
                    (bb1 < bj0 + 16) && (bb3 > bj0);
        unsigned long long m = __ballot(cand);
        if (lane == 0) smask[r * 4 + wv] = m;
    }
    // zmin block reduction (exact: min has no rounding)
    for (int off = 32; off; off >>= 1) zm = fminf(zm, __shfl_xor(zm, off));
    if (lane == 0) sred[wv] = zm;
    __syncthreads();
    const float zmin = fminf(fminf(sred[0], sred[1]), fminf(sred[2], sred[3]));

    // ---- phase 2: ordered compaction of candidate indices ----
    int base[8];
    int cnt = 0;
#pragma unroll
    for (int g = 0; g < 8; ++g) { base[g] = cnt; cnt += __popcll(smask[g]); }
    const unsigned long long lt = (1ull << lane) - 1ull;
#pragma unroll
    for (int r = 0; r < 2; ++r) {
        const int g = r * 4 + wv;
        unsigned long long m = smask[g];
        if ((m >> lane) & 1ull) {
            int pos = base[g] + __popcll(m & lt);
            slist[pos] = tid + r * 256;
        }
    }
    __syncthreads();

    // ---- phase 3: per-pixel loop over surviving triangles ----
    const int j = bj0 + tx;  // yi (fast output axis)
    const int i = bi0 + ty;  // xi
    const float px = lin_at(i);
    const float py = lin_at(j);

    float best = zmin;
    int   bi = -1;
    float bw1 = 0.0f, bw2 = 0.0f;

    for (int k = 0; k < cnt; ++k) {
        const int t = slist[k];
        int4 bb = sbb[t];
        if (i >= bb.x && i < bb.z && j >= bb.y && j < bb.w) {
            float4 f0 = sf0[t];
            float4 f1 = sf1[t];
            // Edge functions: EXACT op-order replication of the reference, no FMA.
            float dax = f0.x - px, day = f0.y - py;
            float dbx = f0.z - px, dby = f0.w - py;
            float dcx = f1.x - px, dcy = f1.y - py;
            float pAB = dax * dby - day * dbx;
            float pBC = dbx * dcy - dby * dcx;
            float pCA = dcx * day - dcy * dax;
            if (pAB > 0.0f && pBC > 0.0f && pCA > 0.0f) {
                float2 f2 = sf2[t];
                float w1 = pAB * f1.w;
                float w2 = pBC * f1.w;
                float w3 = 1.0f - w1 - w2;
                float z = w1 * f1.z + w2 * f2.x + w3 * f2.y;
                if (z >= best) { best = z; bi = t; bw1 = w1; bw2 = w2; }
            }
        }
    }

    // ---- epilogue: interpolate winner, write pixel ----
    float4 o = make_float4(0.0f, 0.0f, 0.0f, 0.0f);
    if (bi >= 0) {
        float4 f0 = sf0[bi];
        float4 f1 = sf1[bi];
        float2 f2 = sf2[bi];
        float w3 = 1.0f - bw1 - bw2;
        float x = bw1 * f0.x + bw2 * f0.z + w3 * f1.x;
        float y = bw1 * f0.y + bw2 * f0.w + w3 * f1.y;
        float z = bw1 * f1.z + bw2 * f2.x + w3 * f2.y;
        o = make_float4(x, y, z, 1.0f);
    }
    ((float4*)out)[i * SIZE + j] = o;
}

extern "C" void kernel_launch(void* const* d_in, const int* in_sizes, int n_in,
                              void* d_out, int out_size, void* d_ws, size_t ws_size,
                              hipStream_t stream) {
    const float* tris = (const float*)d_in[0];
    float* out = (float*)d_out;
    dim3 grid(SIZE / 16, SIZE / 16, 1);
    dim3 block(16, 16, 1);
    render_kernel<<<grid, block, 0, stream>>>(tris, out);
}

// Round 3
// 22.578 us; speedup vs baseline: 4.4395x; 2.1757x over previous
//
#include <hip/hip_runtime.h>

#define SIZE 512
#define NTRI 512

#pragma clang fp contract(off)

__device__ __forceinline__ float lin_at(int i) {
    // Replicates jnp.linspace(-1, 1, 512): for i < 511,
    // s = i/511 (f32 correctly-rounded div), out = (-1)*(1-s) + 1*s = s - (1-s).
    // Endpoint i == 511 is exactly 1.0.
    if (i == SIZE - 1) return 1.0f;
    float s = __fdiv_rn((float)i, 511.0f);
    float u = 1.0f - s;
    return s - u;
}

// Bit-exact reference epilogue for the winning triangle (true division, exact op order).
__device__ __forceinline__ float4 shade(const float* __restrict__ tris, int bi,
                                        float px, float py) {
#pragma clang fp contract(off)
    if (bi < 0) return make_float4(0.0f, 0.0f, 0.0f, 0.0f);
    const float* p = tris + bi * 9;
    float a0 = p[0], a1 = p[1], a2 = p[2];
    float b0 = p[3], b1 = p[4], b2 = p[5];
    float c0 = p[6], c1 = p[7], c2 = p[8];
    float w = (b0 - a0) * (c1 - a1) - (b1 - a1) * (c0 - a0);
    float sw = (fabsf(w) > 1e-8f) ? w : 1.0f;
    float dax = a0 - px, day = a1 - py;
    float dbx = b0 - px, dby = b1 - py;
    float dcx = c0 - px, dcy = c1 - py;
    float pAB = dax * dby - day * dbx;
    float pBC = dbx * dcy - dby * dcx;
    float w1 = __fdiv_rn(pAB, sw);
    float w2 = __fdiv_rn(pBC, sw);
    float w3 = 1.0f - w1 - w2;
    float x = (w1 * a0 + w2 * b0) + w3 * c0;
    float y = (w1 * a1 + w2 * b1) + w3 * c1;
    float z = (w1 * a2 + w2 * b2) + w3 * c2;
    return make_float4(x, y, z, 1.0f);
}

__global__ __launch_bounds__(128) void render_kernel(const float* __restrict__ tris,
                                                     float* __restrict__ out) {
#pragma clang fp contract(off)
    __shared__ float4 cf0[NTRI];   // Ax, Ay, Bx, By   (compacted)
    __shared__ float4 cf1[NTRI];   // Cx, Cy, k1, k2
    __shared__ float2 cf2[NTRI];   // Cz, bitcast(t)
    __shared__ int4   cbb[NTRI];   // bbox, only written for partial candidates
    __shared__ unsigned long long smF[8], smP[8];
    __shared__ float sred[2];

    const int tx = threadIdx.x;          // 0..15  -> j offset
    const int ty = threadIdx.y;          // 0..7
    const int tid = ty * 16 + tx;        // 0..127
    const int lane = tid & 63, wv = tid >> 6;
    const unsigned long long lt = (1ull << lane) - 1ull;

    const int i0 = blockIdx.y * 16;
    const int j0 = blockIdx.x * 16;

    const float pxlo = lin_at(i0), pxhi = lin_at(i0 + 15);
    const float pylo = lin_at(j0), pyhi = lin_at(j0 + 15);

    // ---- phase 1: load 4 tris/thread, preprocess + cull, keep in registers ----
    float va0[4], va1[4], va2[4], vb0[4], vb1[4], vb2[4], vc0[4], vc1[4], vc2[4], vsw[4];
    int   vx0[4], vy0[4], vx1[4], vy1[4];
    bool  vfull[4], vpart[4];

    float zm = 1e30f;
#pragma unroll
    for (int r = 0; r < 4; ++r) {
        const int t = tid + r * 128;
        const float* p = tris + t * 9;
        float a0 = p[0], a1 = p[1], a2 = p[2];
        float b0 = p[3], b1 = p[4], b2 = p[5];
        float c0 = p[6], c1 = p[7], c2 = p[8];
        va0[r] = a0; va1[r] = a1; va2[r] = a2;
        vb0[r] = b0; vb1[r] = b1; vb2[r] = b2;
        vc0[r] = c0; vc1[r] = c1; vc2[r] = c2;

        zm = fminf(zm, fminf(a2, fminf(b2, c2)));

        float w = (b0 - a0) * (c1 - a1) - (b1 - a1) * (c0 - a0);
        bool vw = fabsf(w) > 1e-8f;
        vsw[r] = vw ? w : 1.0f;

        float lox = fminf(fminf(a0, b0), c0);
        float loy = fminf(fminf(a1, b1), c1);
        float hix = fmaxf(fmaxf(a0, b0), c0);
        float hiy = fmaxf(fmaxf(a1, b1), c1);
        int bb0 = (int)((fminf(fmaxf(lox, -1.0f), 1.0f) + 1.0f) * 0.5f * 512.0f);
        int bb1 = (int)((fminf(fmaxf(loy, -1.0f), 1.0f) + 1.0f) * 0.5f * 512.0f);
        int bb2 = (int)((fminf(fmaxf(hix, -1.0f), 1.0f) + 1.0f) * 0.5f * 512.0f);
        int bb3 = (int)((fminf(fmaxf(hiy, -1.0f), 1.0f) + 1.0f) * 0.5f * 512.0f);
        vx0[r] = bb0; vy0[r] = bb1; vx1[r] = bb2; vy1[r] = bb3;

        // Winding cull: all-edges-positive requires w > 0 algebraically (guarded).
        // Bbox-vs-tile cull: complement of per-pixel inbox over this tile.
        bool cand = vw && (w > -1e-4f) &&
                    (bb0 < i0 + 16) && (bb2 > i0) &&
                    (bb1 < j0 + 16) && (bb3 > j0);

        // Edge-vs-tile-rect cull (conservative-exact): edge fn is linear,
        // E = c + gx*px + gy*py; if max over tile rect < -1e-3 << fp error bound,
        // no pixel's computed edge value can be > 0.
        if (cand) {
            float e;
            e = (a0 * b1 - a1 * b0) + fmaxf((a1 - b1) * pxlo, (a1 - b1) * pxhi)
                                    + fmaxf((b0 - a0) * pylo, (b0 - a0) * pyhi);
            cand = cand && (e >= -1e-3f);
            e = (b0 * c1 - b1 * c0) + fmaxf((b1 - c1) * pxlo, (b1 - c1) * pxhi)
                                    + fmaxf((c0 - b0) * pylo, (c0 - b0) * pyhi);
            cand = cand && (e >= -1e-3f);
            e = (c0 * a1 - c1 * a0) + fmaxf((c1 - a1) * pxlo, (c1 - a1) * pxhi)
                                    + fmaxf((a0 - c0) * pylo, (a0 - c0) * pyhi);
            cand = cand && (e >= -1e-3f);
        }

        bool full = cand && (bb0 <= i0) && (bb2 >= i0 + 16) &&
                            (bb1 <= j0) && (bb3 >= j0 + 16);
        vfull[r] = full;
        vpart[r] = cand && !full;

        unsigned long long mF = __ballot(full);
        unsigned long long mP = __ballot(vpart[r]);
        if (lane == 0) { smF[r * 2 + wv] = mF; smP[r * 2 + wv] = mP; }
    }

    // zmin block reduction (min: exact)
    for (int off = 32; off; off >>= 1) zm = fminf(zm, __shfl_xor(zm, off));
    if (lane == 0) sred[wv] = zm;
    __syncthreads();
    const float zmin = fminf(sred[0], sred[1]);

    // ---- phase 2: ordered scatter into compacted lists (full first, partial after) ----
    int baseF[8], baseP[8], c = 0;
#pragma unroll
    for (int g = 0; g < 8; ++g) { baseF[g] = c; c += __popcll(smF[g]); }
    const int cntF = c;
#pragma unroll
    for (int g = 0; g < 8; ++g) { baseP[g] = c; c += __popcll(smP[g]); }
    const int cntT = c;

#pragma unroll
    for (int r = 0; r < 4; ++r) {
        const int g = r * 2 + wv;
        const int t = tid + r * 128;
        if (vfull[r] || vpart[r]) {
            int pos;
            if (vfull[r]) pos = baseF[g] + __popcll(smF[g] & lt);
            else {
                pos = baseP[g] + __popcll(smP[g] & lt);
                cbb[pos] = make_int4(vx0[r], vy0[r], vx1[r], vy1[r]);
            }
            float rsw = __fdiv_rn(1.0f, vsw[r]);
            float k1 = (va2[r] - vc2[r]) * rsw;
            float k2 = (vb2[r] - vc2[r]) * rsw;
            cf0[pos] = make_float4(va0[r], va1[r], vb0[r], vb1[r]);
            cf1[pos] = make_float4(vc0[r], vc1[r], k1, k2);
            cf2[pos] = make_float2(vc2[r], __int_as_float(t));
        }
    }
    __syncthreads();

    // ---- phase 3: per-pixel loop, 2 pixels per thread ----
    const int j  = j0 + tx;
    const int iA = i0 + ty;
    const int iB = iA + 8;
    const float pxA = lin_at(iA);
    const float pxB = lin_at(iB);
    const float py  = lin_at(j);

    float bestA = zmin, bestB = zmin;
    int   biA = -1,     biB = -1;

#define EVAL_PIXEL(PX, COVX, BEST, BI)                                   \
    {                                                                    \
        float dax = f0.x - (PX), day = f0.y - py;                        \
        float dbx = f0.z - (PX), dby = f0.w - py;                        \
        float dcx = f1.x - (PX), dcy = f1.y - py;                        \
        float pAB = dax * dby - day * dbx;                               \
        float pBC = dbx * dcy - dby * dcx;                               \
        float pCA = dcx * day - dcy * dax;                               \
        bool cov = (pAB > 0.0f) & (pBC > 0.0f) & (pCA > 0.0f) & (COVX);  \
        float z = fmaf(pAB, f1.z, fmaf(pBC, f1.w, f2.x));                \
        bool lex = (z > (BEST)) | ((z == (BEST)) & (t > (BI)));          \
        if (cov & lex) { (BEST) = z; (BI) = t; }                         \
    }

    for (int k = 0; k < cntF; ++k) {
        float4 f0 = cf0[k];
        float4 f1 = cf1[k];
        float2 f2 = cf2[k];
        int t = __float_as_int(f2.y);
        EVAL_PIXEL(pxA, true, bestA, biA);
        EVAL_PIXEL(pxB, true, bestB, biB);
    }
    for (int k = cntF; k < cntT; ++k) {
        float4 f0 = cf0[k];
        float4 f1 = cf1[k];
        float2 f2 = cf2[k];
        int4 bb = cbb[k];
        int t = __float_as_int(f2.y);
        bool inJ = (j >= bb.y) & (j < bb.w);
        bool inA = (iA >= bb.x) & (iA < bb.z) & inJ;
        bool inB = (iB >= bb.x) & (iB < bb.z) & inJ;
        EVAL_PIXEL(pxA, inA, bestA, biA);
        EVAL_PIXEL(pxB, inB, bestB, biB);
    }
#undef EVAL_PIXEL

    // ---- epilogue: bit-exact shade of winners ----
    ((float4*)out)[iA * SIZE + j] = shade(tris, biA, pxA, py);
    ((float4*)out)[iB * SIZE + j] = shade(tris, biB, pxB, py);
}

extern "C" void kernel_launch(void* const* d_in, const int* in_sizes, int n_in,
                              void* d_out, int out_size, void* d_ws, size_t ws_size,
                              hipStream_t stream) {
    const float* tris = (const float*)d_in[0];
    float* out = (float*)d_out;
    dim3 grid(SIZE / 16, SIZE / 16, 1);
    dim3 block(16, 8, 1);
    render_kernel<<<grid, block, 0, stream>>>(tris, out);
}

// Round 4
// 17.553 us; speedup vs baseline: 5.7106x; 1.2863x over previous
//
#include <hip/hip_runtime.h>

#define SIZE 512
#define NTRI 512

#pragma clang fp contract(off)

__device__ __forceinline__ float lin_at(int i) {
    // Replicates jnp.linspace(-1, 1, 512): for i < 511,
    // s = i/511 (f32 correctly-rounded div), out = (-1)*(1-s) + 1*s = s - (1-s).
    // Endpoint i == 511 is exactly 1.0.
    if (i == SIZE - 1) return 1.0f;
    float s = __fdiv_rn((float)i, 511.0f);
    float u = 1.0f - s;
    return s - u;
}

// Bit-exact reference epilogue for the winning triangle (true division, exact op order).
__device__ __forceinline__ float4 shade(const float* __restrict__ tris, int bi,
                                        float px, float py) {
#pragma clang fp contract(off)
    if (bi < 0) return make_float4(0.0f, 0.0f, 0.0f, 0.0f);
    const float* p = tris + bi * 9;
    float a0 = p[0], a1 = p[1], a2 = p[2];
    float b0 = p[3], b1 = p[4], b2 = p[5];
    float c0 = p[6], c1 = p[7], c2 = p[8];
    float w = (b0 - a0) * (c1 - a1) - (b1 - a1) * (c0 - a0);
    float sw = (fabsf(w) > 1e-8f) ? w : 1.0f;
    float dax = a0 - px, day = a1 - py;
    float dbx = b0 - px, dby = b1 - py;
    float dcx = c0 - px, dcy = c1 - py;
    float pAB = dax * dby - day * dbx;
    float pBC = dbx * dcy - dby * dcx;
    float w1 = __fdiv_rn(pAB, sw);
    float w2 = __fdiv_rn(pBC, sw);
    float w3 = 1.0f - w1 - w2;
    float x = (w1 * a0 + w2 * b0) + w3 * c0;
    float y = (w1 * a1 + w2 * b1) + w3 * c1;
    float z = (w1 * a2 + w2 * b2) + w3 * c2;
    return make_float4(x, y, z, 1.0f);
}

__global__ __launch_bounds__(128) void render_kernel(const float* __restrict__ tris,
                                                     float* __restrict__ out) {
#pragma clang fp contract(off)
    __shared__ float4 szp[NTRI];   // zc, zx, zy, bitcast(t)   (all classes, compacted)
    __shared__ int4   sbb[NTRI];   // int bbox                 (classes IP, EX)
    __shared__ float4 sv0[NTRI];   // a0, a1, b0, b1           (class EX)
    __shared__ float2 sv1[NTRI];   // c0, c1                   (class EX)
    __shared__ unsigned long long smA[8], smB[8], smC[8];
    __shared__ float sred[2];

    const int tx = threadIdx.x;          // 0..15 -> j offset
    const int ty = threadIdx.y;          // 0..7
    const int tid = ty * 16 + tx;
    const int lane = tid & 63, wv = tid >> 6;
    const unsigned long long lt = (1ull << lane) - 1ull;

    const int i0 = blockIdx.y * 16;
    const int j0 = blockIdx.x * 16;

    const float pxlo = lin_at(i0), pxhi = lin_at(i0 + 15);
    const float pylo = lin_at(j0), pyhi = lin_at(j0 + 15);

    // ---- phase 1: 4 tris/thread: preprocess, cull, classify (registers) ----
    float va0[4], va1[4], va2[4], vb0[4], vb1[4], vb2[4], vc0[4], vc1[4], vc2[4], vsw[4];
    int   vx0[4], vy0[4], vx1[4], vy1[4];
    bool  vIF[4], vIP[4], vEX[4];

    float zm = 1e30f;
#pragma unroll
    for (int r = 0; r < 4; ++r) {
        const int t = tid + r * 128;
        const float* p = tris + t * 9;
        float a0 = p[0], a1 = p[1], a2 = p[2];
        float b0 = p[3], b1 = p[4], b2 = p[5];
        float c0 = p[6], c1 = p[7], c2 = p[8];
        va0[r] = a0; va1[r] = a1; va2[r] = a2;
        vb0[r] = b0; vb1[r] = b1; vb2[r] = b2;
        vc0[r] = c0; vc1[r] = c1; vc2[r] = c2;

        zm = fminf(zm, fminf(a2, fminf(b2, c2)));

        float w = (b0 - a0) * (c1 - a1) - (b1 - a1) * (c0 - a0);
        bool vw = fabsf(w) > 1e-8f;
        vsw[r] = vw ? w : 1.0f;

        float lox = fminf(fminf(a0, b0), c0);
        float loy = fminf(fminf(a1, b1), c1);
        float hix = fmaxf(fmaxf(a0, b0), c0);
        float hiy = fmaxf(fmaxf(a1, b1), c1);
        int bb0 = (int)((fminf(fmaxf(lox, -1.0f), 1.0f) + 1.0f) * 0.5f * 512.0f);
        int bb1 = (int)((fminf(fmaxf(loy, -1.0f), 1.0f) + 1.0f) * 0.5f * 512.0f);
        int bb2 = (int)((fminf(fmaxf(hix, -1.0f), 1.0f) + 1.0f) * 0.5f * 512.0f);
        int bb3 = (int)((fminf(fmaxf(hiy, -1.0f), 1.0f) + 1.0f) * 0.5f * 512.0f);
        vx0[r] = bb0; vy0[r] = bb1; vx1[r] = bb2; vy1[r] = bb3;

        // Winding cull (pAB+pBC+pCA == w algebraically) + bbox-vs-tile cull.
        bool cand = vw && (w > -1e-4f) &&
                    (bb0 < i0 + 16) && (bb2 > i0) &&
                    (bb1 < j0 + 16) && (bb3 > j0);

        // Edge-vs-tile rect: linear edge fn E = c + gx*px + gy*py.
        // max over rect < -1e-3  -> certainly no covered pixel (cull).
        // min over rect > +1e-3  -> edge certainly positive at every tile pixel.
        // Guard 1e-3 >> 1.5e-5 bound on |computed_ref - linear| fp discrepancy.
        bool allIn = false;
        if (cand) {
            float cAB = a0 * b1 - a1 * b0, gxAB = a1 - b1, gyAB = b0 - a0;
            float cBC = b0 * c1 - b1 * c0, gxBC = b1 - c1, gyBC = c0 - b0;
            float cCA = c0 * a1 - c1 * a0, gxCA = c1 - a1, gyCA = a0 - c0;
            float x0, x1, y0, y1, mx, mn;
            x0 = gxAB * pxlo; x1 = gxAB * pxhi; y0 = gyAB * pylo; y1 = gyAB * pyhi;
            mx = cAB + fmaxf(x0, x1) + fmaxf(y0, y1);
            mn = cAB + fminf(x0, x1) + fminf(y0, y1);
            cand = mx >= -1e-3f;
            allIn = mn > 1e-3f;
            x0 = gxBC * pxlo; x1 = gxBC * pxhi; y0 = gyBC * pylo; y1 = gyBC * pyhi;
            mx = cBC + fmaxf(x0, x1) + fmaxf(y0, y1);
            mn = cBC + fminf(x0, x1) + fminf(y0, y1);
            cand = cand && (mx >= -1e-3f);
            allIn = allIn && (mn > 1e-3f);
            x0 = gxCA * pxlo; x1 = gxCA * pxhi; y0 = gyCA * pylo; y1 = gyCA * pyhi;
            mx = cCA + fmaxf(x0, x1) + fmaxf(y0, y1);
            mn = cCA + fminf(x0, x1) + fminf(y0, y1);
            cand = cand && (mx >= -1e-3f);
            allIn = allIn && (mn > 1e-3f);
        }

        bool full = (bb0 <= i0) && (bb2 >= i0 + 16) &&
                    (bb1 <= j0) && (bb3 >= j0 + 16);
        vIF[r] = cand && allIn && full;     // interior, bbox covers tile
        vIP[r] = cand && allIn && !full;    // interior, bbox test needed
        vEX[r] = cand && !allIn;            // exact edge eval needed

        unsigned long long mA = __ballot(vIF[r]);
        unsigned long long mB = __ballot(vIP[r]);
        unsigned long long mC = __ballot(vEX[r]);
        if (lane == 0) { smA[r * 2 + wv] = mA; smB[r * 2 + wv] = mB; smC[r * 2 + wv] = mC; }
    }

    for (int off = 32; off; off >>= 1) zm = fminf(zm, __shfl_xor(zm, off));
    if (lane == 0) sred[wv] = zm;
    __syncthreads();
    const float zmin = fminf(sred[0], sred[1]);

    // ---- phase 2: ordered scatter into 3 compacted segments ----
    int bA[8], bB[8], bC[8], c = 0;
#pragma unroll
    for (int g = 0; g < 8; ++g) { bA[g] = c; c += __popcll(smA[g]); }
    const int cntA = c;
#pragma unroll
    for (int g = 0; g < 8; ++g) { bB[g] = c; c += __popcll(smB[g]); }
    const int cntB = c;
#pragma unroll
    for (int g = 0; g < 8; ++g) { bC[g] = c; c += __popcll(smC[g]); }
    const int cntC = c;

#pragma unroll
    for (int r = 0; r < 4; ++r) {
        if (vIF[r] || vIP[r] || vEX[r]) {
            const int g = r * 2 + wv;
            const int t = tid + r * 128;
            int pos;
            if (vIF[r])      pos = bA[g] + __popcll(smA[g] & lt);
            else if (vIP[r]) pos = bB[g] + __popcll(smB[g] & lt);
            else             pos = bC[g] + __popcll(smC[g] & lt);

            float a0 = va0[r], a1 = va1[r], b0 = vb0[r], b1 = vb1[r];
            float c0 = vc0[r], c1 = vc1[r];
            float rsw = __fdiv_rn(1.0f, vsw[r]);
            float k1 = (va2[r] - vc2[r]) * rsw;
            float k2 = (vb2[r] - vc2[r]) * rsw;
            float cAB = a0 * b1 - a1 * b0, gxAB = a1 - b1, gyAB = b0 - a0;
            float cBC = b0 * c1 - b1 * c0, gxBC = b1 - c1, gyBC = c0 - b0;
            float zc = vc2[r] + k1 * cAB + k2 * cBC;
            float zx = k1 * gxAB + k2 * gxBC;
            float zy = k1 * gyAB + k2 * gyBC;
            szp[pos] = make_float4(zc, zx, zy, __int_as_float(t));
            if (!vIF[r]) sbb[pos] = make_int4(vx0[r], vy0[r], vx1[r], vy1[r]);
            if (vEX[r]) {
                sv0[pos] = make_float4(a0, a1, b0, b1);
                sv1[pos] = make_float2(c0, c1);
            }
        }
    }
    __syncthreads();

    // ---- phase 3: per-pixel loop, 2 pixels/thread, 3 segments ----
    const int j  = j0 + tx;
    const int iA = i0 + ty;
    const int iB = iA + 8;
    const float pxA = lin_at(iA);
    const float pxB = lin_at(iB);
    const float py  = lin_at(j);

    float bestA = zmin, bestB = zmin;
    float bfA = __int_as_float(-1), bfB = __int_as_float(-1);

    // S1: interior + full bbox: z-plane only.
#pragma unroll 4
    for (int k = 0; k < cntA; ++k) {
        float4 zp = szp[k];
        float base = fmaf(zp.z, py, zp.x);
        float zA = fmaf(zp.y, pxA, base);
        float zB = fmaf(zp.y, pxB, base);
        if (zA >= bestA) { bestA = zA; bfA = zp.w; }
        if (zB >= bestB) { bestB = zB; bfB = zp.w; }
    }
    // S2: interior + partial bbox.
#pragma unroll 4
    for (int k = cntA; k < cntB; ++k) {
        float4 zp = szp[k];
        int4 bb = sbb[k];
        float base = fmaf(zp.z, py, zp.x);
        float zA = fmaf(zp.y, pxA, base);
        float zB = fmaf(zp.y, pxB, base);
        bool inJ = (j >= bb.y) & (j < bb.w);
        bool inA = (iA >= bb.x) & (iA < bb.z) & inJ;
        bool inB = (iB >= bb.x) & (iB < bb.z) & inJ;
        if (inA & (zA >= bestA)) { bestA = zA; bfA = zp.w; }
        if (inB & (zB >= bestB)) { bestB = zB; bfB = zp.w; }
    }
    // S3: exact edge evaluation (reference op order) + bbox.
#pragma unroll 2
    for (int k = cntB; k < cntC; ++k) {
        float4 zp = szp[k];
        float4 f0 = sv0[k];
        float2 f1 = sv1[k];
        int4 bb = sbb[k];
        float day = f0.y - py, dby = f0.w - py, dcy = f1.y - py;
        float base = fmaf(zp.z, py, zp.x);
        bool inJ = (j >= bb.y) & (j < bb.w);
        {
            float dax = f0.x - pxA, dbx = f0.z - pxA, dcx = f1.x - pxA;
            float pAB = dax * dby - day * dbx;
            float pBC = dbx * dcy - dby * dcx;
            float pCA = dcx * day - dcy * dax;
            bool cov = (pAB > 0.0f) & (pBC > 0.0f) & (pCA > 0.0f) &
                       (iA >= bb.x) & (iA < bb.z) & inJ;
            float zA = fmaf(zp.y, pxA, base);
            if (cov & (zA >= bestA)) { bestA = zA; bfA = zp.w; }
        }
        {
            float dax = f0.x - pxB, dbx = f0.z - pxB, dcx = f1.x - pxB;
            float pAB = dax * dby - day * dbx;
            float pBC = dbx * dcy - dby * dcx;
            float pCA = dcx * day - dcy * dax;
            bool cov = (pAB > 0.0f) & (pBC > 0.0f) & (pCA > 0.0f) &
                       (iB >= bb.x) & (iB < bb.z) & inJ;
            float zB = fmaf(zp.y, pxB, base);
            if (cov & (zB >= bestB)) { bestB = zB; bfB = zp.w; }
        }
    }

    // ---- epilogue: bit-exact shade of winners ----
    ((float4*)out)[iA * SIZE + j] = shade(tris, __float_as_int(bfA), pxA, py);
    ((float4*)out)[iB * SIZE + j] = shade(tris, __float_as_int(bfB), pxB, py);
}

extern "C" void kernel_launch(void* const* d_in, const int* in_sizes, int n_in,
                              void* d_out, int out_size, void* d_ws, size_t ws_size,
                              hipStream_t stream) {
    const float* tris = (const float*)d_in[0];
    float* out = (float*)d_out;
    dim3 grid(SIZE / 16, SIZE / 16, 1);
    dim3 block(16, 8, 1);
    render_kernel<<<grid, block, 0, stream>>>(tris, out);
}